// Round 1
// baseline (300.974 us; speedup 1.0000x reference)
//
#include <hip/hip_runtime.h>
#include <stdint.h>

// ---- problem constants ----
// z: [32][256][32][32] fp32, kappa:[1], codebook:[512][256], gumbel:[32768][512]
// out: z_to_decoder [32][256][32][32] (8388608) + loss + perplexity
#define KCODES 512
#define DDIM   256

typedef float v4f __attribute__((ext_vector_type(4)));
typedef short v8s __attribute__((ext_vector_type(8)));

__device__ __forceinline__ uint16_t f2bf(float x) {
  uint32_t u = __float_as_uint(x);
  u = u + 0x7fffu + ((u >> 16) & 1u);   // round-to-nearest-even
  return (uint16_t)(u >> 16);
}

// lg is [32][512] fp32 with 5-bit XOR swizzle inside 32-col groups (conflict-free
// both for row-major 16-lane writes and full-wave column sweeps)
__device__ __forceinline__ int lgoff(int r, int c) {
  return (r << 9) + (c & ~31) + ((c ^ r) & 31);
}

// ---- workspace layout (bytes) ----
// [0]       cbn  bf16 [512][256]   (row-normalized codebook)
// [262144]  cbt  bf16 [256][512]   (transposed copy for GEMM2 B-frags)
// [524288]  shadow fp32 [16][512]  (avg_probs partial accumulators)
// [557056]  scal fp32 [3]: {sum p*logp, sum z^2, sum e*(l2+mx)/Se}

__global__ __launch_bounds__(64) void vq_prep(const float* __restrict__ cb,
                                              char* __restrict__ ws) {
  const int blk = blockIdx.x, t = threadIdx.x;
  uint16_t* cbn = (uint16_t*)ws;
  uint16_t* cbt = (uint16_t*)(ws + 262144);
  float* shadow = (float*)(ws + 524288);
  float* scal   = (float*)(ws + 557056);
  if (blk < 512) {
    float v[4]; float s = 0.f;
#pragma unroll
    for (int i = 0; i < 4; i++) { v[i] = cb[blk * 256 + t + 64 * i]; s += v[i] * v[i]; }
#pragma unroll
    for (int m = 1; m < 64; m <<= 1) s += __shfl_xor(s, m, 64);
    const float sc = 1.0f / sqrtf(s);
#pragma unroll
    for (int i = 0; i < 4; i++) {
      const int d = t + 64 * i;
      const uint16_t h = f2bf(v[i] * sc);
      cbn[blk * 256 + d] = h;
      cbt[d * 512 + blk] = h;
    }
  } else if (blk < 528) {
    const int j = blk - 512;
#pragma unroll
    for (int i = 0; i < 8; i++) shadow[j * 512 + t + 64 * i] = 0.f;
  } else {
    if (t < 3) scal[t] = 0.f;
  }
}

__global__ __launch_bounds__(256, 2) void vq_main(const float* __restrict__ z,
                                                  const float* __restrict__ kappa,
                                                  const float* __restrict__ gum,
                                                  char* __restrict__ ws,
                                                  float* __restrict__ out) {
  __shared__ float s_lg[32 * 512];   // 64 KB: logits -> l2
  __shared__ float s_aux[2400];      // 9.6 KB: colsums / e-chunks / small arrays

  const int t = threadIdx.x;
  const int w = t >> 6;              // wave 0..3
  const int lane = t & 63;
  const int q = lane >> 4;           // quad
  const int m = lane & 15;
  const int bi = blockIdx.x;         // 0..1023
  const int b = bi >> 5;             // batch image
  const int wh0 = (bi & 31) << 5;    // spatial base (32 consecutive wh)
  const int R0 = bi << 5;            // global row base

  const uint16_t* cbn = (const uint16_t*)ws;
  const uint16_t* cbt = (const uint16_t*)(ws + 262144);
  float* shadow = (float*)(ws + 524288);
  float* scal   = (float*)(ws + 557056);

  float kq = fminf(fmaxf(kappa[0], 1e-5f), 1e5f);

  // ---------- phase 0: sum of z^2 (fp32-exact, coalesced) ----------
  {
    float zs = 0.f;
    const int d0 = t >> 3;
    const int jj = (t & 7) << 2;
    const float* zb = z + ((size_t)b << 18) + wh0 + jj;
#pragma unroll
    for (int i = 0; i < 8; i++) {
      const int d = d0 + (i << 5);
      const float4 vv = *(const float4*)(zb + (d << 10));
      zs += vv.x * vv.x + vv.y * vv.y + vv.z * vv.z + vv.w * vv.w;
    }
#pragma unroll
    for (int mm = 1; mm < 64; mm <<= 1) zs += __shfl_xor(zs, mm, 64);
    if (lane == 0) atomicAdd(&scal[1], zs);
  }

  // ---------- GEMM1: logits[32][512] = kq * z @ cbn^T ----------
  {
    v4f acc0[8], acc1[8];
#pragma unroll
    for (int i = 0; i < 8; i++) { acc0[i] = (v4f)0.f; acc1[i] = (v4f)0.f; }
    const int c0 = w << 7;  // wave's 128-code slice
    const float* zrow = z + ((size_t)b << 18) + wh0 + m;  // + k*1024 (+16 for tile1)
#pragma unroll
    for (int ks = 0; ks < 8; ks++) {
      const int kbase = (ks << 5) + (q << 3);
      union { v8s v; uint16_t u[8]; } a0, a1;
#pragma unroll
      for (int j = 0; j < 8; j++) {
        const int k = kbase + j;
        a0.u[j] = f2bf(zrow[(k << 10)]);
        a1.u[j] = f2bf(zrow[(k << 10) + 16]);
      }
#pragma unroll
      for (int ct = 0; ct < 8; ct++) {
        const int c = c0 + (ct << 4) + m;
        const v8s bfr = *(const v8s*)(cbn + c * 256 + kbase);
        acc0[ct] = __builtin_amdgcn_mfma_f32_16x16x32_bf16(a0.v, bfr, acc0[ct], 0, 0, 0);
        acc1[ct] = __builtin_amdgcn_mfma_f32_16x16x32_bf16(a1.v, bfr, acc1[ct], 0, 0, 0);
      }
    }
    // C/D layout: row = q*4+reg, col = lane&15
#pragma unroll
    for (int ct = 0; ct < 8; ct++) {
#pragma unroll
      for (int reg = 0; reg < 4; reg++) {
        const int r0 = q * 4 + reg;
        const int c = c0 + (ct << 4) + m;
        s_lg[lgoff(r0, c)] = acc0[ct][reg] * kq;
        s_lg[lgoff(r0 + 16, c)] = acc1[ct][reg] * kq;
      }
    }
  }
  __syncthreads();

  float* s_cs = s_aux;          // [4][512] colsums (transient)
  float* s_mx = s_aux + 2304;   // [32]
  float* s_Se = s_aux + 2336;   // [32]

  // ---------- merged softmax pass: max, l2, S, p*logp, p column sums ----------
  {
    float colacc[8];
#pragma unroll
    for (int i = 0; i < 8; i++) colacc[i] = 0.f;
    float kd = 0.f;
#pragma unroll 1
    for (int j = 0; j < 8; j++) {
      const int r = (w << 3) + j;
      float v[8], ev[8];
      float mx = -1e30f;
#pragma unroll
      for (int i = 0; i < 8; i++) {
        v[i] = s_lg[lgoff(r, lane + (i << 6))];
        mx = fmaxf(mx, v[i]);
      }
#pragma unroll
      for (int mm = 1; mm < 64; mm <<= 1) mx = fmaxf(mx, __shfl_xor(mx, mm, 64));
      float S = 0.f, T1 = 0.f;
#pragma unroll
      for (int i = 0; i < 8; i++) {
        const float l2 = fmaxf(v[i] - mx, -50.0f);  // ref clip; upper clip is dead
        const float e = __expf(l2);
        ev[i] = e; S += e; T1 += e * l2;
        s_lg[lgoff(r, lane + (i << 6))] = l2;       // store l2 back
      }
#pragma unroll
      for (int mm = 1; mm < 64; mm <<= 1) {
        S += __shfl_xor(S, mm, 64); T1 += __shfl_xor(T1, mm, 64);
      }
      const float rS = 1.0f / S;
      kd += T1 * rS - __logf(S);
#pragma unroll
      for (int i = 0; i < 8; i++) colacc[i] += ev[i] * rS;
      if (lane == 0) s_mx[r] = mx;
    }
    if (lane == 0) atomicAdd(&scal[0], kd);
#pragma unroll
    for (int i = 0; i < 8; i++) s_cs[(w << 9) + lane + (i << 6)] = colacc[i];
  }
  __syncthreads();
  // combine 4 wave colsums -> shadow accumulator (16-way spread atomics)
  {
#pragma unroll
    for (int h = 0; h < 2; h++) {
      const int c = t + (h << 8);
      const float s = s_cs[c] + s_cs[512 + c] + s_cs[1024 + c] + s_cs[1536 + c];
      atomicAdd(&shadow[((bi & 15) << 9) + c], s);
    }
  }
  __syncthreads();

  // ---------- GEMM2: zq = (e_raw @ cbn) / Se, e computed chunk-by-chunk ----------
  short* s_ec = (short*)s_aux;          // [2][32][72] bf16 chunks
  const int rme = t >> 3;               // this thread's row (wave-local set)
  const int ce8 = (t & 7) << 3;
  const float* gr = gum + (size_t)(R0 + rme) * 512 + ce8;
  const float mxr = s_mx[rme];
  float se = 0.f, ce = 0.f;

  v4f acc2[2][4];
#pragma unroll
  for (int a = 0; a < 2; a++)
#pragma unroll
    for (int nt = 0; nt < 4; nt++) acc2[a][nt] = (v4f)0.f;
  const int d0 = w << 6;  // wave's 64-dim slice

  auto compute_chunk = [&](int cc) {
    const int buf = cc & 1;
    const float4 g0 = *(const float4*)(gr + (cc << 6));
    const float4 g1 = *(const float4*)(gr + (cc << 6) + 4);
    const float gg[8] = {g0.x, g0.y, g0.z, g0.w, g1.x, g1.y, g1.z, g1.w};
    union { v8s v; uint16_t u[8]; } eb;
#pragma unroll
    for (int i = 0; i < 8; i++) {
      const int c = (cc << 6) + ce8 + i;
      const float l2 = s_lg[lgoff(rme, c)];
      const float L = -__logf(gg[i] + 1e-10f) + 1e-10f;          // > 0 always
      const float er = __expf(2.0f * (l2 - __logf(L)));          // exp((l2+g)/T)
      se += er;
      ce += er * (l2 + mxr);   // e * raw_logit  (z.zq cross-term, analytic)
      eb.u[i] = f2bf(er);
    }
    *(v8s*)(s_ec + buf * 2304 + rme * 72 + ce8) = eb.v;
  };
  auto mfma_chunk = [&](int cc) {
    const int buf = cc & 1;
#pragma unroll
    for (int ks = 0; ks < 2; ks++) {
      const v8s a0 = *(const v8s*)(s_ec + buf * 2304 + m * 72 + (ks << 5) + (q << 3));
      const v8s a1 = *(const v8s*)(s_ec + buf * 2304 + (m + 16) * 72 + (ks << 5) + (q << 3));
#pragma unroll
      for (int nt = 0; nt < 4; nt++) {
        const int d = d0 + (nt << 4) + m;
        const v8s bfr = *(const v8s*)(cbt + d * 512 + (cc << 6) + (ks << 5) + (q << 3));
        acc2[0][nt] = __builtin_amdgcn_mfma_f32_16x16x32_bf16(a0, bfr, acc2[0][nt], 0, 0, 0);
        acc2[1][nt] = __builtin_amdgcn_mfma_f32_16x16x32_bf16(a1, bfr, acc2[1][nt], 0, 0, 0);
      }
    }
  };

  compute_chunk(0);
  __syncthreads();
#pragma unroll 1
  for (int cc = 0; cc < 8; cc++) {
    mfma_chunk(cc);
    if (cc < 7) compute_chunk(cc + 1);
    __syncthreads();
  }

  // per-row Se and cross-term reductions (8 lanes per row, then per-wave)
#pragma unroll
  for (int mm = 1; mm < 8; mm <<= 1) {
    se += __shfl_xor(se, mm, 64); ce += __shfl_xor(ce, mm, 64);
  }
  float cr = ce / se;   // uniform within each 8-lane row group
#pragma unroll
  for (int mm = 8; mm < 64; mm <<= 1) cr += __shfl_xor(cr, mm, 64);
  if (lane == 0) atomicAdd(&scal[2], cr);
  if ((t & 7) == 0) s_Se[rme] = se;
  __syncthreads();

  // ---------- epilogue: scale by 1/Se, store z_to_decoder ----------
  {
    float* ob = out + ((size_t)b << 18) + wh0;
#pragma unroll
    for (int t2 = 0; t2 < 2; t2++) {
#pragma unroll
      for (int reg = 0; reg < 4; reg++) {
        const int r = (t2 << 4) + (q << 2) + reg;
        const float rs = 1.0f / s_Se[r];
#pragma unroll
        for (int nt = 0; nt < 4; nt++) {
          const int d = d0 + (nt << 4) + m;
          ob[(d << 10) + r] = acc2[t2][nt][reg] * rs;
        }
      }
    }
  }
}

__global__ __launch_bounds__(512) void vq_final(const float* __restrict__ kappa,
                                                char* __restrict__ ws,
                                                float* __restrict__ out) {
  __shared__ float red[8];
  const int t = threadIdx.x;
  const float* shadow = (const float*)(ws + 524288);
  const float* scal   = (const float*)(ws + 557056);
  float s = 0.f;
#pragma unroll
  for (int j = 0; j < 16; j++) s += shadow[(j << 9) + t];
  float avg = fmaxf(s * (1.0f / 32768.0f), 1e-10f);
  float term = avg * __logf(avg + 1e-10f);
#pragma unroll
  for (int mm = 1; mm < 64; mm <<= 1) term += __shfl_xor(term, mm, 64);
  if ((t & 63) == 0) red[t >> 6] = term;
  __syncthreads();
  if (t == 0) {
    float H = 0.f;
#pragma unroll
    for (int i = 0; i < 8; i++) H += red[i];
    const float perpl = __expf(-H);
    const float kq = fminf(fmaxf(kappa[0], 1e-5f), 1e5f);
    // loss = sum(p logp)/32 + (kq*sum(z^2) - sum(e*(l2+mx)))/32
    const float loss = (scal[0] + kq * scal[1] - scal[2]) * (1.0f / 32.0f);
    out[8388608] = loss;
    out[8388609] = perpl;
  }
}

extern "C" void kernel_launch(void* const* d_in, const int* in_sizes, int n_in,
                              void* d_out, int out_size, void* d_ws, size_t ws_size,
                              hipStream_t stream) {
  const float* z     = (const float*)d_in[0];
  const float* kappa = (const float*)d_in[1];
  const float* cb    = (const float*)d_in[2];
  const float* gum   = (const float*)d_in[3];
  char* ws = (char*)d_ws;
  float* out = (float*)d_out;
  hipLaunchKernelGGL(vq_prep,  dim3(529), dim3(64),  0, stream, cb, ws);
  hipLaunchKernelGGL(vq_main,  dim3(1024), dim3(256), 0, stream, z, kappa, gum, ws, out);
  hipLaunchKernelGGL(vq_final, dim3(1),   dim3(512), 0, stream, kappa, ws, out);
}

// Round 2
// 215.404 us; speedup vs baseline: 1.3973x; 1.3973x over previous
//
#include <hip/hip_runtime.h>
#include <stdint.h>

// ---- problem constants ----
// z: [32][256][32][32] fp32, kappa:[1], codebook:[512][256], gumbel:[32768][512]
// out: z_to_decoder [32][256][32][32] (8388608) + loss + perplexity

typedef float v4f __attribute__((ext_vector_type(4)));
typedef short v8s __attribute__((ext_vector_type(8)));

#define ZA_STR 264   // shorts; row = 528B, 16B-aligned, bank-spread
#define L2_STR 520   // shorts; row = 1040B, 16B-aligned, bank-spread

__device__ __forceinline__ uint16_t f2bf(float x) {
  uint32_t u = __float_as_uint(x);
  u = u + 0x7fffu + ((u >> 16) & 1u);   // round-to-nearest-even
  return (uint16_t)(u >> 16);
}
__device__ __forceinline__ float bf2f(uint16_t h) {
  return __uint_as_float(((uint32_t)h) << 16);
}

// ---- workspace layout (bytes) ----
// [0]       cbn2 bf16 [128K]  frag-permuted normalized codebook for GEMM1 B
//           addr = ((ks*8+ct)*4+w)*512 + (q*16+m)*8 + j   (code=w*128+ct*16+m, k=ks*32+q*8+j)
// [262144]  cbt2 bf16 [128K]  frag-permuted transposed codebook for GEMM2 B
//           addr = (((cc*2+ks)*4+nt)*4+w)*512 + (q*16+m)*8 + j (k=cc*64+ks*32+q*8+j, d=w*64+nt*16+m)
// [524288]  shadow fp32 [16][512]  avg_probs partial accumulators
// [557056]  scal fp32 [3]: {sum p*logp, sum z^2, sum e*(l2+mx)/Se}

__global__ __launch_bounds__(64) void vq_prep(const float* __restrict__ cb,
                                              char* __restrict__ ws) {
  const int blk = blockIdx.x, t = threadIdx.x;
  uint16_t* cbn2 = (uint16_t*)ws;
  uint16_t* cbt2 = (uint16_t*)(ws + 262144);
  float* shadow = (float*)(ws + 524288);
  float* scal   = (float*)(ws + 557056);
  if (blk < 512) {
    const int c = blk;
    float v[4]; float s = 0.f;
#pragma unroll
    for (int i = 0; i < 4; i++) { v[i] = cb[c * 256 + t + 64 * i]; s += v[i] * v[i]; }
#pragma unroll
    for (int mm = 1; mm < 64; mm <<= 1) s += __shfl_xor(s, mm, 64);
    const float sc = 1.0f / sqrtf(s);
    const int w = c >> 7, ct = (c >> 4) & 7, mcol = c & 15;
    const int cc = c >> 6, k2 = (c >> 5) & 1, qq = (c >> 3) & 3, j2 = c & 7;
#pragma unroll
    for (int i = 0; i < 4; i++) {
      const int d = t + 64 * i;
      const uint16_t h = f2bf(v[i] * sc);
      const int ks = d >> 5, q3 = (d >> 3) & 3, j = d & 7;
      cbn2[((ks * 8 + ct) * 4 + w) * 512 + (q3 * 16 + mcol) * 8 + j] = h;
      const int wd = d >> 6, nt = (d >> 4) & 3, md = d & 15;
      cbt2[(((cc * 2 + k2) * 4 + nt) * 4 + wd) * 512 + (qq * 16 + md) * 8 + j2] = h;
    }
  } else if (blk < 528) {
    const int j = blk - 512;
#pragma unroll
    for (int i = 0; i < 8; i++) shadow[j * 512 + t + 64 * i] = 0.f;
  } else {
    if (t < 3) scal[t] = 0.f;
  }
}

__global__ __launch_bounds__(256, 3) void vq_main(const float* __restrict__ z,
                                                  const float* __restrict__ kappa,
                                                  const float* __restrict__ gum,
                                                  char* __restrict__ ws,
                                                  float* __restrict__ out) {
  __shared__ char s_buf0[32 * ZA_STR * 2];   // 16896B: za bf16[32][264] | s_ec short[2][32][72]
  __shared__ char s_buf1[256 * 33 * 4];      // 33792B: l2 bf16[32][520] | zqT fp32[256][33]
  __shared__ float s_pm[128], s_pS[128], s_pT[128];
  __shared__ float s_M[32], s_rS[32], s_kd[32], s_rSe[32], s_red[8];

  const int t = threadIdx.x;
  const int w = t >> 6, lane = t & 63, q = lane >> 4, m = lane & 15;
  const int bi = blockIdx.x, b = bi >> 5, wh0 = (bi & 31) << 5;
  const int R0 = bi << 5;

  const uint16_t* cbn2 = (const uint16_t*)ws;
  const uint16_t* cbt2 = (const uint16_t*)(ws + 262144);
  float* shadow = (float*)(ws + 524288);
  float* scal   = (float*)(ws + 557056);

  uint16_t* za  = (uint16_t*)s_buf0;
  uint16_t* l2s = (uint16_t*)s_buf1;

  const float kq = fminf(fmaxf(kappa[0], 1e-5f), 1e5f);

  // ---------- staging: z -> LDS bf16 (A-layout) fused with sum(z^2) ----------
  {
    float zs = 0.f;
    const int whb = (t & 7) << 2, dT = t >> 3;
    const float* zb = z + ((size_t)b << 18) + wh0 + whb;
#pragma unroll
    for (int s = 0; s < 8; s++) {
      const int d = dT + (s << 5);
      const float4 v = *(const float4*)(zb + (d << 10));
      zs += v.x * v.x + v.y * v.y + v.z * v.z + v.w * v.w;
      za[(whb + 0) * ZA_STR + d] = f2bf(v.x);
      za[(whb + 1) * ZA_STR + d] = f2bf(v.y);
      za[(whb + 2) * ZA_STR + d] = f2bf(v.z);
      za[(whb + 3) * ZA_STR + d] = f2bf(v.w);
    }
#pragma unroll
    for (int mm = 1; mm < 64; mm <<= 1) zs += __shfl_xor(zs, mm, 64);
    if (lane == 0) s_red[w] = zs;
  }
  __syncthreads();
  if (t == 0) atomicAdd(&scal[1], s_red[0] + s_red[1] + s_red[2] + s_red[3]);

  // ---------- GEMM1: logits = kq * z @ cbn^T ; acc stays in registers ----------
  v4f acc0[8], acc1[8];
#pragma unroll
  for (int i = 0; i < 8; i++) { acc0[i] = (v4f)0.f; acc1[i] = (v4f)0.f; }
  {
    const uint16_t* bp  = cbn2 + (w << 9) + (lane << 3);    // coalesced frag loads
    const uint16_t* a0p = za + m * ZA_STR;
    const uint16_t* a1p = za + (m + 16) * ZA_STR;
#pragma unroll
    for (int ks = 0; ks < 8; ks++) {
      const v8s a0 = *(const v8s*)(a0p + (ks << 5) + (q << 3));
      const v8s a1 = *(const v8s*)(a1p + (ks << 5) + (q << 3));
#pragma unroll
      for (int ct = 0; ct < 8; ct++) {
        const v8s bf = *(const v8s*)(bp + (((ks << 3) + ct) << 11));
        acc0[ct] = __builtin_amdgcn_mfma_f32_16x16x32_bf16(a0, bf, acc0[ct], 0, 0, 0);
        acc1[ct] = __builtin_amdgcn_mfma_f32_16x16x32_bf16(a1, bf, acc1[ct], 0, 0, 0);
      }
    }
  }

  // ---------- per-wave per-row online softmax stats from accumulators ----------
  {
    auto stats_half = [&](v4f (&acc)[8], int half) {
#pragma unroll
      for (int reg = 0; reg < 4; reg++) {
        float mx = -1e30f;
#pragma unroll
        for (int ct = 0; ct < 8; ct++) mx = fmaxf(mx, kq * acc[ct][reg]);
#pragma unroll
        for (int mm = 1; mm < 16; mm <<= 1) mx = fmaxf(mx, __shfl_xor(mx, mm, 64));
        float S = 0.f, T = 0.f;
#pragma unroll
        for (int ct = 0; ct < 8; ct++) {
          const float d = kq * acc[ct][reg] - mx;
          const float e = __expf(d);
          S += e; T += d * e;
        }
#pragma unroll
        for (int mm = 1; mm < 16; mm <<= 1) { S += __shfl_xor(S, mm, 64); T += __shfl_xor(T, mm, 64); }
        if (m == 0) {
          const int r = half * 16 + q * 4 + reg;
          s_pm[(w << 5) + r] = mx; s_pS[(w << 5) + r] = S; s_pT[(w << 5) + r] = T;
        }
      }
    };
    stats_half(acc0, 0);
    stats_half(acc1, 1);
  }
  __syncthreads();
  if (t < 32) {  // combine 4 wave-partials per row (online-softmax merge)
    float M = s_pm[t];
    M = fmaxf(M, s_pm[32 + t]); M = fmaxf(M, s_pm[64 + t]); M = fmaxf(M, s_pm[96 + t]);
    float S = 0.f, T = 0.f;
#pragma unroll
    for (int ww = 0; ww < 4; ww++) {
      const float dm = s_pm[ww * 32 + t] - M;
      const float al = __expf(dm);
      S += s_pS[ww * 32 + t] * al;
      T += (s_pT[ww * 32 + t] + dm * s_pS[ww * 32 + t]) * al;
    }
    const float rS = 1.0f / S;
    s_M[t] = M; s_rS[t] = rS; s_kd[t] = T * rS - __logf(S);
  }
  __syncthreads();

  // ---------- pass2: p column sums + l2 -> LDS bf16 ----------
  {
    const int c0 = w << 7;
    float colacc[8];
#pragma unroll
    for (int i = 0; i < 8; i++) colacc[i] = 0.f;
    auto pass2_half = [&](v4f (&acc)[8], int half) {
#pragma unroll
      for (int reg = 0; reg < 4; reg++) {
        const int r = half * 16 + q * 4 + reg;
        const float Mr = s_M[r], rSr = s_rS[r];
        uint16_t* lrow = l2s + r * L2_STR + c0 + m;
#pragma unroll
        for (int ct = 0; ct < 8; ct++) {
          const float d = fmaxf(kq * acc[ct][reg] - Mr, -50.0f);
          const float e = __expf(d);
          colacc[ct] += e * rSr;
          lrow[ct << 4] = f2bf(d);
        }
      }
    };
    pass2_half(acc0, 0);
    pass2_half(acc1, 1);
#pragma unroll
    for (int i = 0; i < 8; i++) {
      colacc[i] += __shfl_xor(colacc[i], 16, 64);
      colacc[i] += __shfl_xor(colacc[i], 32, 64);
    }
    if (q == 0) {
      float* sh = shadow + ((bi & 15) << 9) + c0 + m;
#pragma unroll
      for (int i = 0; i < 8; i++) atomicAdd(&sh[i << 4], colacc[i]);
    }
    if (w == 0) {  // kld_discrete partial: one atomic per block
      float kd = s_kd[lane & 31];
#pragma unroll
      for (int mm = 1; mm < 64; mm <<= 1) kd += __shfl_xor(kd, mm, 64);
      if (lane == 0) atomicAdd(&scal[0], 0.5f * kd);
    }
  }
  __syncthreads();

  // ---------- GEMM2: zq = (e @ cbn) / Se, e in 64-code chunks (dbuf) ----------
  short* s_ec = (short*)s_buf0;
  const int rme = t >> 3, ce8 = (t & 7) << 3;
  const float* gr = gum + (size_t)(R0 + rme) * 512 + ce8;
  const float mxr = s_M[rme];
  float se = 0.f, ce = 0.f;
  v4f acc2a[4], acc2b[4];
#pragma unroll
  for (int i = 0; i < 4; i++) { acc2a[i] = (v4f)0.f; acc2b[i] = (v4f)0.f; }

  auto compute_chunk = [&](int cc) {
    const int buf = cc & 1;
    const float4 g0 = *(const float4*)(gr + (cc << 6));
    const float4 g1 = *(const float4*)(gr + (cc << 6) + 4);
    const float gg[8] = {g0.x, g0.y, g0.z, g0.w, g1.x, g1.y, g1.z, g1.w};
    union { v8s v; uint16_t u[8]; } lv, eb;
    lv.v = *(const v8s*)(l2s + rme * L2_STR + (cc << 6) + ce8);
#pragma unroll
    for (int i = 0; i < 8; i++) {
      const float l2 = bf2f(lv.u[i]);
      const float L = -__logf(gg[i] + 1e-10f) + 1e-10f;
      const float er = __expf(2.0f * (l2 - __logf(L)));   // exp((l2+g)/T)
      se += er; ce += er * (l2 + mxr);                    // analytic z.zq cross-term
      eb.u[i] = f2bf(er);
    }
    *(v8s*)(s_ec + buf * 2304 + rme * 72 + ce8) = eb.v;
  };
  auto mfma_chunk = [&](int cc) {
    const int buf = cc & 1;
#pragma unroll
    for (int ks = 0; ks < 2; ks++) {
      const v8s a0 = *(const v8s*)(s_ec + buf * 2304 + m * 72 + (ks << 5) + (q << 3));
      const v8s a1 = *(const v8s*)(s_ec + buf * 2304 + (m + 16) * 72 + (ks << 5) + (q << 3));
      const uint16_t* bp2 = cbt2 + (((cc << 1) + ks) << 13) + (w << 9) + (lane << 3);
#pragma unroll
      for (int nt = 0; nt < 4; nt++) {
        const v8s bf = *(const v8s*)(bp2 + (nt << 11));
        acc2a[nt] = __builtin_amdgcn_mfma_f32_16x16x32_bf16(a0, bf, acc2a[nt], 0, 0, 0);
        acc2b[nt] = __builtin_amdgcn_mfma_f32_16x16x32_bf16(a1, bf, acc2b[nt], 0, 0, 0);
      }
    }
  };

  compute_chunk(0);
  __syncthreads();
#pragma unroll 1
  for (int cc = 0; cc < 8; cc++) {
    mfma_chunk(cc);
    if (cc < 7) compute_chunk(cc + 1);
    __syncthreads();
  }

  // per-row Se + cross-term; one scal[2] atomic per block
#pragma unroll
  for (int mm = 1; mm < 8; mm <<= 1) { se += __shfl_xor(se, mm, 64); ce += __shfl_xor(ce, mm, 64); }
  {
    float cr = ((t & 7) == 0) ? (ce / se) : 0.f;
#pragma unroll
    for (int mm = 8; mm < 64; mm <<= 1) cr += __shfl_xor(cr, mm, 64);
    if (lane == 0) s_red[w] = cr;
    if ((t & 7) == 0) s_rSe[rme] = 1.0f / se;
  }
  __syncthreads();
  if (t == 0) atomicAdd(&scal[2], s_red[0] + s_red[1] + s_red[2] + s_red[3]);

  // ---------- epilogue: transpose through LDS, coalesced float4 stores ----------
  {
    float* zqT = (float*)s_buf1;   // [256][33]
    const int d0 = w << 6;
    float rsA[4], rsB[4];
#pragma unroll
    for (int reg = 0; reg < 4; reg++) {
      rsA[reg] = s_rSe[q * 4 + reg];
      rsB[reg] = s_rSe[16 + q * 4 + reg];
    }
#pragma unroll
    for (int nt = 0; nt < 4; nt++) {
      const int d = d0 + (nt << 4) + m;
#pragma unroll
      for (int reg = 0; reg < 4; reg++) {
        zqT[d * 33 + q * 4 + reg]      = acc2a[nt][reg] * rsA[reg];
        zqT[d * 33 + 16 + q * 4 + reg] = acc2b[nt][reg] * rsB[reg];
      }
    }
  }
  __syncthreads();
  {
    const int whb = (t & 7) << 2, dT = t >> 3;
    float* ob = out + ((size_t)b << 18) + wh0 + whb;
    const float* zqT = (const float*)s_buf1;
#pragma unroll
    for (int s = 0; s < 8; s++) {
      const int d = dT + (s << 5);
      const float* zr = zqT + d * 33 + whb;
      float4 v; v.x = zr[0]; v.y = zr[1]; v.z = zr[2]; v.w = zr[3];
      *(float4*)(ob + (d << 10)) = v;
    }
  }
}

__global__ __launch_bounds__(512) void vq_final(const float* __restrict__ kappa,
                                                char* __restrict__ ws,
                                                float* __restrict__ out) {
  __shared__ float red[8];
  const int t = threadIdx.x;
  const float* shadow = (const float*)(ws + 524288);
  const float* scal   = (const float*)(ws + 557056);
  float s = 0.f;
#pragma unroll
  for (int j = 0; j < 16; j++) s += shadow[(j << 9) + t];
  float avg = fmaxf(s * (1.0f / 32768.0f), 1e-10f);
  float term = avg * __logf(avg + 1e-10f);
#pragma unroll
  for (int mm = 1; mm < 64; mm <<= 1) term += __shfl_xor(term, mm, 64);
  if ((t & 63) == 0) red[t >> 6] = term;
  __syncthreads();
  if (t == 0) {
    float H = 0.f;
#pragma unroll
    for (int i = 0; i < 8; i++) H += red[i];
    const float perpl = __expf(-H);
    const float kq = fminf(fmaxf(kappa[0], 1e-5f), 1e5f);
    const float loss = (scal[0] + kq * scal[1] - scal[2]) * (1.0f / 32.0f);
    out[8388608] = loss;
    out[8388609] = perpl;
  }
}

extern "C" void kernel_launch(void* const* d_in, const int* in_sizes, int n_in,
                              void* d_out, int out_size, void* d_ws, size_t ws_size,
                              hipStream_t stream) {
  const float* z     = (const float*)d_in[0];
  const float* kappa = (const float*)d_in[1];
  const float* cb    = (const float*)d_in[2];
  const float* gum   = (const float*)d_in[3];
  char* ws = (char*)d_ws;
  float* out = (float*)d_out;
  hipLaunchKernelGGL(vq_prep,  dim3(529),  dim3(64),  0, stream, cb, ws);
  hipLaunchKernelGGL(vq_main,  dim3(1024), dim3(256), 0, stream, z, kappa, gum, ws, out);
  hipLaunchKernelGGL(vq_final, dim3(1),    dim3(512), 0, stream, kappa, ws, out);
}

// Round 3
// 207.434 us; speedup vs baseline: 1.4509x; 1.0384x over previous
//
#include <hip/hip_runtime.h>
#include <stdint.h>

// ---- problem constants ----
// z: [32][256][32][32] fp32, kappa:[1], codebook:[512][256], gumbel:[32768][512]
// out: z_to_decoder [32][256][32][32] (8388608) + loss + perplexity

typedef float v4f __attribute__((ext_vector_type(4)));
typedef short v8s __attribute__((ext_vector_type(8)));
typedef short v4s __attribute__((ext_vector_type(4)));

#define ZA_STR 264   // shorts; za row stride (16B aligned)
#define L2_STR 520   // shorts; l2s row stride (16B aligned)
#define EC_STR 40    // shorts; e-chunk row stride (16B aligned)

__device__ __forceinline__ uint16_t f2bf(float x) {
  uint32_t u = __float_as_uint(x);
  u = u + 0x7fffu + ((u >> 16) & 1u);   // round-to-nearest-even
  return (uint16_t)(u >> 16);
}
__device__ __forceinline__ float bf2f(uint16_t h) {
  return __uint_as_float(((uint32_t)h) << 16);
}

// ---- workspace layout (bytes) ----
// [0]       cbn2 bf16 [128K]  frag-permuted normalized codebook for GEMM1 B
//           addr = ((ks*8+ct)*4+w)*512 + (q*16+m)*8 + j   (code=w*128+ct*16+m, k=ks*32+q*8+j)
// [262144]  cbt2 bf16 [128K]  frag-permuted transposed codebook for GEMM2 B
//           addr = (cc32*4+nt)*4+wd)*512 + (q*16+md)*8 + j (k=cc32*32+q*8+j, d=wd*64+nt*16+md)
// [524288]  shadow fp32 [16][512]  avg_probs partial accumulators
// [557056]  scal fp32 [3]: {sum p*logp, sum z^2, sum e*(l2+mx)/Se}
// [557072]  rnorm fp32 [512]

// prep0: per-code reciprocal norms + zero shadow/scal
__global__ __launch_bounds__(64) void vq_prep0(const float* __restrict__ cb,
                                               char* __restrict__ ws) {
  const int blk = blockIdx.x, t = threadIdx.x;
  float* shadow = (float*)(ws + 524288);
  float* scal   = (float*)(ws + 557056);
  float* rnorm  = (float*)(ws + 557072);
  if (blk < 512) {
    float s = 0.f;
#pragma unroll
    for (int i = 0; i < 4; i++) { const float v = cb[blk * 256 + t + 64 * i]; s += v * v; }
#pragma unroll
    for (int mm = 1; mm < 64; mm <<= 1) s += __shfl_xor(s, mm, 64);
    if (t == 0) rnorm[blk] = 1.0f / sqrtf(s);
  } else if (blk < 528) {
    const int j = blk - 512;
#pragma unroll
    for (int i = 0; i < 8; i++) shadow[j * 512 + t + 64 * i] = 0.f;
  } else {
    if (t < 3) scal[t] = 0.f;
  }
}

// prep1: build both permuted codebook tables with coalesced reads + 16B writes
__global__ __launch_bounds__(256) void vq_prep1(const float* __restrict__ cb,
                                                char* __restrict__ ws) {
  const int b = blockIdx.x, t = threadIdx.x;
  uint16_t* cbn2 = (uint16_t*)ws;
  uint16_t* cbt2 = (uint16_t*)(ws + 262144);
  const float* rnorm = (const float*)(ws + 557072);
  union { v8s v; uint16_t u[8]; } pk;
  if (b < 64) {
    const int g = b * 256 + t;           // 16384 chunks: code x d-chunk
    const int code = g >> 5, dch = g & 31;
    const float rn = rnorm[code];
    const float4 f0 = *(const float4*)(cb + code * 256 + dch * 8);
    const float4 f1 = *(const float4*)(cb + code * 256 + dch * 8 + 4);
    pk.u[0] = f2bf(f0.x * rn); pk.u[1] = f2bf(f0.y * rn);
    pk.u[2] = f2bf(f0.z * rn); pk.u[3] = f2bf(f0.w * rn);
    pk.u[4] = f2bf(f1.x * rn); pk.u[5] = f2bf(f1.y * rn);
    pk.u[6] = f2bf(f1.z * rn); pk.u[7] = f2bf(f1.w * rn);
    const int w = code >> 7, ct = (code >> 4) & 7, mcol = code & 15;
    const int ks = dch >> 2, q3 = dch & 3;
    *(v8s*)(cbn2 + ((ks * 8 + ct) * 4 + w) * 512 + (q3 * 16 + mcol) * 8) = pk.v;
  } else {
    const int g = (b - 64) * 256 + t;    // 16384 chunks: cgroup x d
    const int cgroup = g >> 8, d = g & 255;
#pragma unroll
    for (int j = 0; j < 8; j++) {
      const int c = cgroup * 8 + j;
      pk.u[j] = f2bf(cb[c * 256 + d] * rnorm[c]);
    }
    const int cc = cgroup >> 2, qq = cgroup & 3;           // cc32 = cgroup>>2? no:
    // cgroup in [0,64): k = cgroup*8+j = cc32*32 + q*8 + j -> cc32 = cgroup>>2, q = cgroup&3
    const int wd = d >> 6, nt = (d >> 4) & 3, md = d & 15;
    *(v8s*)(cbt2 + ((cc * 4 + nt) * 4 + wd) * 512 + (qq * 16 + md) * 8) = pk.v;
  }
}

__global__ __launch_bounds__(256, 4) void vq_main(const float* __restrict__ z,
                                                  const float* __restrict__ kappa,
                                                  const float* __restrict__ gum,
                                                  char* __restrict__ ws,
                                                  float* __restrict__ out) {
  __shared__ char s_A[33280];   // za short[32][264] -> l2s short[32][520]
  __shared__ char s_B[5120];    // pm/pS/pT fp32[3][128] -> s_ec short[2][32][40]
  __shared__ float s_M[32], s_rS[32], s_kd[32], s_rSe[32], s_red[8];

  const int t = threadIdx.x;
  const int w = t >> 6, lane = t & 63, q = lane >> 4, m = lane & 15;
  const int bi = blockIdx.x, b = bi >> 5, wh0 = (bi & 31) << 5;
  const int R0 = bi << 5;

  const uint16_t* cbn2 = (const uint16_t*)ws;
  const uint16_t* cbt2 = (const uint16_t*)(ws + 262144);
  float* shadow = (float*)(ws + 524288);
  float* scal   = (float*)(ws + 557056);

  uint16_t* za  = (uint16_t*)s_A;
  uint16_t* l2s = (uint16_t*)s_A;
  float* s_pm = (float*)s_B;
  float* s_pS = (float*)s_B + 128;
  float* s_pT = (float*)s_B + 256;
  short* s_ec = (short*)s_B;

  const float kq = fminf(fmaxf(kappa[0], 1e-5f), 1e5f);

  // GEMM2 per-thread mapping (used for gumbel prefetch)
  const int row = t >> 3, c4 = (t & 7) << 2;
  const float* gbase = gum + (size_t)(R0 + row) * 512 + c4;

  // ---------- staging: z -> LDS bf16 (A-layout) fused with sum(z^2) ----------
  {
    float zs = 0.f;
    const int whb = (t & 7) << 2, dT = t >> 3;
    const float* zb = z + ((size_t)b << 18) + wh0 + whb;
#pragma unroll
    for (int s = 0; s < 8; s++) {
      const int d = dT + (s << 5);
      const float4 v = *(const float4*)(zb + (d << 10));
      zs += v.x * v.x + v.y * v.y + v.z * v.z + v.w * v.w;
      za[(whb + 0) * ZA_STR + d] = f2bf(v.x);
      za[(whb + 1) * ZA_STR + d] = f2bf(v.y);
      za[(whb + 2) * ZA_STR + d] = f2bf(v.z);
      za[(whb + 3) * ZA_STR + d] = f2bf(v.w);
    }
#pragma unroll
    for (int mm = 1; mm < 64; mm <<= 1) zs += __shfl_xor(zs, mm, 64);
    if (lane == 0) s_red[w] = zs;
  }

  // ---------- gumbel rolling prefetch, depth 4 (covered by GEMM1+softmax) ----------
  float4 gq[4];
#pragma unroll
  for (int i = 0; i < 4; i++) gq[i] = *(const float4*)(gbase + (i << 5));

  __syncthreads();
  if (t == 0) atomicAdd(&scal[1], s_red[0] + s_red[1] + s_red[2] + s_red[3]);

  // ---------- GEMM1: logits = kq * z @ cbn^T ; acc stays in registers ----------
  v4f acc0[8], acc1[8];
#pragma unroll
  for (int i = 0; i < 8; i++) { acc0[i] = (v4f)0.f; acc1[i] = (v4f)0.f; }
  {
    const uint16_t* bp  = cbn2 + (w << 9) + (lane << 3);
    const uint16_t* a0p = za + m * ZA_STR;
    const uint16_t* a1p = za + (m + 16) * ZA_STR;
#pragma unroll
    for (int ks = 0; ks < 8; ks++) {
      const v8s a0 = *(const v8s*)(a0p + (ks << 5) + (q << 3));
      const v8s a1 = *(const v8s*)(a1p + (ks << 5) + (q << 3));
#pragma unroll
      for (int ct = 0; ct < 8; ct++) {
        const v8s bf = *(const v8s*)(bp + (((ks << 3) + ct) << 11));
        acc0[ct] = __builtin_amdgcn_mfma_f32_16x16x32_bf16(a0, bf, acc0[ct], 0, 0, 0);
        acc1[ct] = __builtin_amdgcn_mfma_f32_16x16x32_bf16(a1, bf, acc1[ct], 0, 0, 0);
      }
    }
  }
  // fold kq once
#pragma unroll
  for (int i = 0; i < 8; i++) { acc0[i] *= kq; acc1[i] *= kq; }

  // ---------- per-wave per-row softmax stats from accumulators ----------
  {
    auto stats_half = [&](v4f (&acc)[8], int half) {
#pragma unroll
      for (int reg = 0; reg < 4; reg++) {
        float mx = -1e30f;
#pragma unroll
        for (int ct = 0; ct < 8; ct++) mx = fmaxf(mx, acc[ct][reg]);
#pragma unroll
        for (int mm = 1; mm < 16; mm <<= 1) mx = fmaxf(mx, __shfl_xor(mx, mm, 64));
        float S = 0.f, T = 0.f;
#pragma unroll
        for (int ct = 0; ct < 8; ct++) {
          const float d = acc[ct][reg] - mx;
          const float e = __expf(d);
          S += e; T += d * e;
        }
#pragma unroll
        for (int mm = 1; mm < 16; mm <<= 1) { S += __shfl_xor(S, mm, 64); T += __shfl_xor(T, mm, 64); }
        if (m == 0) {
          const int r = half * 16 + q * 4 + reg;
          s_pm[(w << 5) + r] = mx; s_pS[(w << 5) + r] = S; s_pT[(w << 5) + r] = T;
        }
      }
    };
    stats_half(acc0, 0);
    stats_half(acc1, 1);
  }
  __syncthreads();
  if (t < 32) {  // merge 4 wave-partials per row (online-softmax merge)
    float M = s_pm[t];
    M = fmaxf(M, s_pm[32 + t]); M = fmaxf(M, s_pm[64 + t]); M = fmaxf(M, s_pm[96 + t]);
    float S = 0.f, T = 0.f;
#pragma unroll
    for (int ww = 0; ww < 4; ww++) {
      const float dm = s_pm[ww * 32 + t] - M;
      const float al = __expf(dm);
      S += s_pS[ww * 32 + t] * al;
      T += (s_pT[ww * 32 + t] + dm * s_pS[ww * 32 + t]) * al;
    }
    const float rS = 1.0f / S;
    s_M[t] = M; s_rS[t] = rS; s_kd[t] = T * rS - __logf(S);
  }
  __syncthreads();

  // ---------- pass2: p column sums + l2 -> LDS bf16 (za region is dead now) ----------
  {
    const int c0 = w << 7;
    float colacc[8];
#pragma unroll
    for (int i = 0; i < 8; i++) colacc[i] = 0.f;
    auto pass2_half = [&](v4f (&acc)[8], int half) {
#pragma unroll
      for (int reg = 0; reg < 4; reg++) {
        const int r = half * 16 + q * 4 + reg;
        const float Mr = s_M[r], rSr = s_rS[r];
        uint16_t* lrow = l2s + r * L2_STR + c0 + m;
#pragma unroll
        for (int ct = 0; ct < 8; ct++) {
          const float d = fmaxf(acc[ct][reg] - Mr, -50.0f);
          const float e = __expf(d);
          colacc[ct] += e * rSr;
          lrow[ct << 4] = f2bf(d);
        }
      }
    };
    pass2_half(acc0, 0);
    pass2_half(acc1, 1);
#pragma unroll
    for (int i = 0; i < 8; i++) {
      colacc[i] += __shfl_xor(colacc[i], 16, 64);
      colacc[i] += __shfl_xor(colacc[i], 32, 64);
    }
    if (q == 0) {
      float* sh = shadow + ((bi & 15) << 9) + c0 + m;
#pragma unroll
      for (int i = 0; i < 8; i++) atomicAdd(&sh[i << 4], colacc[i]);
    }
    if (w == 0) {  // kld_discrete partial: one atomic per block
      float kd = s_kd[lane & 31];
#pragma unroll
      for (int mm = 1; mm < 64; mm <<= 1) kd += __shfl_xor(kd, mm, 64);
      if (lane == 0) atomicAdd(&scal[0], 0.5f * kd);
    }
  }
  __syncthreads();

  // ---------- GEMM2: zq = (e @ cbn) / Se, 16 chunks x 32 codes, LDS dbuf ----------
  const float mxr = s_M[row];
  float se = 0.f, ce = 0.f;
  v4f acc2a[4], acc2b[4];
#pragma unroll
  for (int i = 0; i < 4; i++) { acc2a[i] = (v4f)0.f; acc2b[i] = (v4f)0.f; }

  auto compute_chunk = [&](int cc) {
    const int buf = cc & 1;
    const float4 u = gq[cc & 3];
    const float uu[4] = {u.x, u.y, u.z, u.w};
    union { v4s v; uint16_t h[4]; } lv, eb;
    lv.v = *(const v4s*)(l2s + row * L2_STR + (cc << 5) + c4);
#pragma unroll
    for (int i = 0; i < 4; i++) {
      const float l2 = bf2f(lv.h[i]);
      const float L = -__logf(uu[i] + 1e-10f) + 1e-10f;
      const float er = __expf(2.0f * (l2 - __logf(L)));   // exp((l2+g)/T)
      se += er; ce += er * (l2 + mxr);                    // analytic z.zq cross-term
      eb.h[i] = f2bf(er);
    }
    *(v4s*)(s_ec + buf * 1280 + row * EC_STR + c4) = eb.v;
    if (cc + 4 < 16) gq[cc & 3] = *(const float4*)(gbase + ((cc + 4) << 5));
  };
  auto mfma_chunk = [&](int cc) {
    const int buf = cc & 1;
    const v8s a0 = *(const v8s*)(s_ec + buf * 1280 + m * EC_STR + (q << 3));
    const v8s a1 = *(const v8s*)(s_ec + buf * 1280 + (m + 16) * EC_STR + (q << 3));
    const uint16_t* bp2 = cbt2 + (cc << 13) + (w << 9) + (lane << 3);
#pragma unroll
    for (int nt = 0; nt < 4; nt++) {
      const v8s bf = *(const v8s*)(bp2 + (nt << 11));
      acc2a[nt] = __builtin_amdgcn_mfma_f32_16x16x32_bf16(a0, bf, acc2a[nt], 0, 0, 0);
      acc2b[nt] = __builtin_amdgcn_mfma_f32_16x16x32_bf16(a1, bf, acc2b[nt], 0, 0, 0);
    }
  };

  compute_chunk(0);
  __syncthreads();
#pragma unroll
  for (int cc = 0; cc < 16; cc++) {
    mfma_chunk(cc);
    if (cc < 15) compute_chunk(cc + 1);
    __syncthreads();
  }

  // per-row Se + cross-term; one scal[2] atomic per block
#pragma unroll
  for (int mm = 1; mm < 8; mm <<= 1) { se += __shfl_xor(se, mm, 64); ce += __shfl_xor(ce, mm, 64); }
  {
    float cr = ((t & 7) == 0) ? (ce / se) : 0.f;
#pragma unroll
    for (int mm = 8; mm < 64; mm <<= 1) cr += __shfl_xor(cr, mm, 64);
    if (lane == 0) s_red[w] = cr;
    if ((t & 7) == 0) s_rSe[row] = 1.0f / se;
  }
  __syncthreads();
  if (t == 0) atomicAdd(&scal[2], s_red[0] + s_red[1] + s_red[2] + s_red[3]);

  // ---------- epilogue: direct strided stores (L2 write-combines: proven r1/r2) ----------
  {
    float* ob = out + ((size_t)b << 18) + wh0;
    const int d0 = w << 6;
    float rsA[4], rsB[4];
#pragma unroll
    for (int reg = 0; reg < 4; reg++) {
      rsA[reg] = s_rSe[q * 4 + reg];
      rsB[reg] = s_rSe[16 + q * 4 + reg];
    }
#pragma unroll
    for (int nt = 0; nt < 4; nt++) {
      const int d = d0 + (nt << 4) + m;
#pragma unroll
      for (int reg = 0; reg < 4; reg++) {
        ob[(d << 10) + q * 4 + reg]      = acc2a[nt][reg] * rsA[reg];
        ob[(d << 10) + 16 + q * 4 + reg] = acc2b[nt][reg] * rsB[reg];
      }
    }
  }
}

__global__ __launch_bounds__(512) void vq_final(const float* __restrict__ kappa,
                                                char* __restrict__ ws,
                                                float* __restrict__ out) {
  __shared__ float red[8];
  const int t = threadIdx.x;
  const float* shadow = (const float*)(ws + 524288);
  const float* scal   = (const float*)(ws + 557056);
  float s = 0.f;
#pragma unroll
  for (int j = 0; j < 16; j++) s += shadow[(j << 9) + t];
  float avg = fmaxf(s * (1.0f / 32768.0f), 1e-10f);
  float term = avg * __logf(avg + 1e-10f);
#pragma unroll
  for (int mm = 1; mm < 64; mm <<= 1) term += __shfl_xor(term, mm, 64);
  if ((t & 63) == 0) red[t >> 6] = term;
  __syncthreads();
  if (t == 0) {
    float H = 0.f;
#pragma unroll
    for (int i = 0; i < 8; i++) H += red[i];
    const float perpl = __expf(-H);
    const float kq = fminf(fmaxf(kappa[0], 1e-5f), 1e5f);
    const float loss = (scal[0] + kq * scal[1] - scal[2]) * (1.0f / 32.0f);
    out[8388608] = loss;
    out[8388609] = perpl;
  }
}

extern "C" void kernel_launch(void* const* d_in, const int* in_sizes, int n_in,
                              void* d_out, int out_size, void* d_ws, size_t ws_size,
                              hipStream_t stream) {
  const float* z     = (const float*)d_in[0];
  const float* kappa = (const float*)d_in[1];
  const float* cb    = (const float*)d_in[2];
  const float* gum   = (const float*)d_in[3];
  char* ws = (char*)d_ws;
  float* out = (float*)d_out;
  hipLaunchKernelGGL(vq_prep0, dim3(529),  dim3(64),  0, stream, cb, ws);
  hipLaunchKernelGGL(vq_prep1, dim3(128),  dim3(256), 0, stream, cb, ws);
  hipLaunchKernelGGL(vq_main,  dim3(1024), dim3(256), 0, stream, z, kappa, gum, ws, out);
  hipLaunchKernelGGL(vq_final, dim3(1),    dim3(512), 0, stream, kappa, ws, out);
}

// Round 4
// 200.561 us; speedup vs baseline: 1.5007x; 1.0343x over previous
//
#include <hip/hip_runtime.h>
#include <stdint.h>

// ---- problem constants ----
// z: [32][256][32][32] fp32, kappa:[1], codebook:[512][256], gumbel:[32768][512]
// out: z_to_decoder [32][256][32][32] (8388608) + loss + perplexity

typedef float v4f __attribute__((ext_vector_type(4)));
typedef short v8s __attribute__((ext_vector_type(8)));
typedef short v4s __attribute__((ext_vector_type(4)));

#define ZA_STR 264   // shorts; za row stride (16B aligned)
#define L2_STR 520   // shorts; e/er row stride (1040B = 65*16B, 16B aligned)

__device__ __forceinline__ uint16_t f2bf(float x) {
  uint32_t u = __float_as_uint(x);
  u = u + 0x7fffu + ((u >> 16) & 1u);   // round-to-nearest-even
  return (uint16_t)(u >> 16);
}
__device__ __forceinline__ float bf2f(uint16_t h) {
  return __uint_as_float(((uint32_t)h) << 16);
}

// ---- workspace layout (bytes) ----
// [0]       cbn2 bf16 [128K]  frag-permuted normalized codebook for GEMM1 B
// [262144]  cbt2 bf16 [128K]  frag-permuted transposed codebook for GEMM2 B
// [524288]  shadow fp32 [16][512]  avg_probs partial accumulators
// [557056]  scal fp32 [3]: {sum p*logp, sum z^2, sum e*(l2+mx)/Se}
// [557072]  rnorm fp32 [512]

__global__ __launch_bounds__(64) void vq_prep0(const float* __restrict__ cb,
                                               char* __restrict__ ws) {
  const int blk = blockIdx.x, t = threadIdx.x;
  float* shadow = (float*)(ws + 524288);
  float* scal   = (float*)(ws + 557056);
  float* rnorm  = (float*)(ws + 557072);
  if (blk < 512) {
    float s = 0.f;
#pragma unroll
    for (int i = 0; i < 4; i++) { const float v = cb[blk * 256 + t + 64 * i]; s += v * v; }
#pragma unroll
    for (int mm = 1; mm < 64; mm <<= 1) s += __shfl_xor(s, mm, 64);
    if (t == 0) rnorm[blk] = 1.0f / sqrtf(s);
  } else if (blk < 528) {
    const int j = blk - 512;
#pragma unroll
    for (int i = 0; i < 8; i++) shadow[j * 512 + t + 64 * i] = 0.f;
  } else {
    if (t < 3) scal[t] = 0.f;
  }
}

__global__ __launch_bounds__(256) void vq_prep1(const float* __restrict__ cb,
                                                char* __restrict__ ws) {
  const int b = blockIdx.x, t = threadIdx.x;
  uint16_t* cbn2 = (uint16_t*)ws;
  uint16_t* cbt2 = (uint16_t*)(ws + 262144);
  const float* rnorm = (const float*)(ws + 557072);
  union { v8s v; uint16_t u[8]; } pk;
  if (b < 64) {
    const int g = b * 256 + t;           // code x d-chunk
    const int code = g >> 5, dch = g & 31;
    const float rn = rnorm[code];
    const float4 f0 = *(const float4*)(cb + code * 256 + dch * 8);
    const float4 f1 = *(const float4*)(cb + code * 256 + dch * 8 + 4);
    pk.u[0] = f2bf(f0.x * rn); pk.u[1] = f2bf(f0.y * rn);
    pk.u[2] = f2bf(f0.z * rn); pk.u[3] = f2bf(f0.w * rn);
    pk.u[4] = f2bf(f1.x * rn); pk.u[5] = f2bf(f1.y * rn);
    pk.u[6] = f2bf(f1.z * rn); pk.u[7] = f2bf(f1.w * rn);
    const int w = code >> 7, ct = (code >> 4) & 7, mcol = code & 15;
    const int ks = dch >> 2, q3 = dch & 3;
    *(v8s*)(cbn2 + ((ks * 8 + ct) * 4 + w) * 512 + (q3 * 16 + mcol) * 8) = pk.v;
  } else {
    const int g = (b - 64) * 256 + t;    // cgroup x d
    const int cgroup = g >> 8, d = g & 255;
#pragma unroll
    for (int j = 0; j < 8; j++) {
      const int c = cgroup * 8 + j;
      pk.u[j] = f2bf(cb[c * 256 + d] * rnorm[c]);
    }
    const int cc = cgroup >> 2, qq = cgroup & 3;   // k = cc*32 + qq*8 + j
    const int wd = d >> 6, nt = (d >> 4) & 3, md = d & 15;
    *(v8s*)(cbt2 + ((cc * 4 + nt) * 4 + wd) * 512 + (qq * 16 + md) * 8) = pk.v;
  }
}

__global__ __launch_bounds__(256, 4) void vq_main(const float* __restrict__ z,
                                                  const float* __restrict__ kappa,
                                                  const float* __restrict__ gum,
                                                  char* __restrict__ ws,
                                                  float* __restrict__ out) {
  __shared__ char s_A[33280];   // za short[32][264] -> e/er short[32][520] (in-place)
  __shared__ float s_pm[128], s_pS[128], s_pT[128];
  __shared__ float s_M[32], s_rS[32], s_kd[32], s_rSe[32], s_red[8];

  const int t = threadIdx.x;
  const int w = t >> 6, lane = t & 63, q = lane >> 4, m = lane & 15;
  const int bi = blockIdx.x, b = bi >> 5, wh0 = (bi & 31) << 5;
  const int R0 = bi << 5;

  const uint16_t* cbn2 = (const uint16_t*)ws;
  const uint16_t* cbt2 = (const uint16_t*)(ws + 262144);
  float* shadow = (float*)(ws + 524288);
  float* scal   = (float*)(ws + 557056);

  uint16_t* za  = (uint16_t*)s_A;
  uint16_t* l2s = (uint16_t*)s_A;

  const float kq = fminf(fmaxf(kappa[0], 1e-5f), 1e5f);

  // transform-phase mapping (also used for gumbel prefetch)
  const int row = t >> 3, c4 = (t & 7) << 2;
  const float* gbase = gum + (size_t)(R0 + row) * 512 + c4;

  // ---------- staging: z -> LDS bf16 (A-layout) fused with sum(z^2) ----------
  {
    float zs = 0.f;
    const int whb = (t & 7) << 2, dT = t >> 3;
    const float* zb = z + ((size_t)b << 18) + wh0 + whb;
#pragma unroll
    for (int s = 0; s < 8; s++) {
      const int d = dT + (s << 5);
      const float4 v = *(const float4*)(zb + (d << 10));
      zs += v.x * v.x + v.y * v.y + v.z * v.z + v.w * v.w;
      za[(whb + 0) * ZA_STR + d] = f2bf(v.x);
      za[(whb + 1) * ZA_STR + d] = f2bf(v.y);
      za[(whb + 2) * ZA_STR + d] = f2bf(v.z);
      za[(whb + 3) * ZA_STR + d] = f2bf(v.w);
    }
#pragma unroll
    for (int mm = 1; mm < 64; mm <<= 1) zs += __shfl_xor(zs, mm, 64);
    if (lane == 0) s_red[w] = zs;
  }

  // gumbel rolling prefetch, depth 4 (latency covered by GEMM1 + softmax)
  float4 gq[4];
#pragma unroll
  for (int i = 0; i < 4; i++) gq[i] = *(const float4*)(gbase + (i << 5));

  __syncthreads();  // B1
  if (t == 0) atomicAdd(&scal[1], s_red[0] + s_red[1] + s_red[2] + s_red[3]);

  // ---------- GEMM1: logits = kq * z @ cbn^T ; acc stays in registers ----------
  v4f acc0[8], acc1[8];
#pragma unroll
  for (int i = 0; i < 8; i++) { acc0[i] = (v4f)0.f; acc1[i] = (v4f)0.f; }
  {
    const uint16_t* bp  = cbn2 + (w << 9) + (lane << 3);
    const uint16_t* a0p = za + m * ZA_STR;
    const uint16_t* a1p = za + (m + 16) * ZA_STR;
#pragma unroll
    for (int ks = 0; ks < 8; ks++) {
      const v8s a0 = *(const v8s*)(a0p + (ks << 5) + (q << 3));
      const v8s a1 = *(const v8s*)(a1p + (ks << 5) + (q << 3));
#pragma unroll
      for (int ct = 0; ct < 8; ct++) {
        const v8s bf = *(const v8s*)(bp + (((ks << 3) + ct) << 11));
        acc0[ct] = __builtin_amdgcn_mfma_f32_16x16x32_bf16(a0, bf, acc0[ct], 0, 0, 0);
        acc1[ct] = __builtin_amdgcn_mfma_f32_16x16x32_bf16(a1, bf, acc1[ct], 0, 0, 0);
      }
    }
  }
#pragma unroll
  for (int i = 0; i < 8; i++) { acc0[i] *= kq; acc1[i] *= kq; }

  // ---------- per-wave per-row softmax stats from accumulators ----------
  {
    auto stats_half = [&](v4f (&acc)[8], int half) {
#pragma unroll
      for (int reg = 0; reg < 4; reg++) {
        float mx = -1e30f;
#pragma unroll
        for (int ct = 0; ct < 8; ct++) mx = fmaxf(mx, acc[ct][reg]);
#pragma unroll
        for (int mm = 1; mm < 16; mm <<= 1) mx = fmaxf(mx, __shfl_xor(mx, mm, 64));
        float S = 0.f, T = 0.f;
#pragma unroll
        for (int ct = 0; ct < 8; ct++) {
          const float d = acc[ct][reg] - mx;
          const float e = __expf(d);
          S += e; T += d * e;
        }
#pragma unroll
        for (int mm = 1; mm < 16; mm <<= 1) { S += __shfl_xor(S, mm, 64); T += __shfl_xor(T, mm, 64); }
        if (m == 0) {
          const int r = half * 16 + q * 4 + reg;
          s_pm[(w << 5) + r] = mx; s_pS[(w << 5) + r] = S; s_pT[(w << 5) + r] = T;
        }
      }
    };
    stats_half(acc0, 0);
    stats_half(acc1, 1);
  }
  __syncthreads();  // B2
  if (t < 32) {  // merge 4 wave-partials per row (online-softmax merge)
    float M = s_pm[t];
    M = fmaxf(M, s_pm[32 + t]); M = fmaxf(M, s_pm[64 + t]); M = fmaxf(M, s_pm[96 + t]);
    float S = 0.f, T = 0.f;
#pragma unroll
    for (int ww = 0; ww < 4; ww++) {
      const float dm = s_pm[ww * 32 + t] - M;
      const float al = __expf(dm);
      S += s_pS[ww * 32 + t] * al;
      T += (s_pT[ww * 32 + t] + dm * s_pS[ww * 32 + t]) * al;
    }
    const float rS = 1.0f / S;
    s_M[t] = M; s_rS[t] = rS; s_kd[t] = T * rS - __logf(S);
  }
  __syncthreads();  // B3

  // ---------- pass2: p column sums + e=exp(l2) -> LDS bf16 (za is dead) ----------
  {
    const int c0 = w << 7;
    float colacc[8];
#pragma unroll
    for (int i = 0; i < 8; i++) colacc[i] = 0.f;
    auto pass2_half = [&](v4f (&acc)[8], int half) {
#pragma unroll
      for (int reg = 0; reg < 4; reg++) {
        const int r = half * 16 + q * 4 + reg;
        const float Mr = s_M[r], rSr = s_rS[r];
        uint16_t* lrow = l2s + r * L2_STR + c0 + m;
#pragma unroll
        for (int ct = 0; ct < 8; ct++) {
          const float d = fmaxf(acc[ct][reg] - Mr, -50.0f);
          const float e = __expf(d);
          colacc[ct] += e * rSr;
          lrow[ct << 4] = f2bf(e);     // store e (not l2): er = (e/L)^2 later
        }
      }
    };
    pass2_half(acc0, 0);
    pass2_half(acc1, 1);
#pragma unroll
    for (int i = 0; i < 8; i++) {
      colacc[i] += __shfl_xor(colacc[i], 16, 64);
      colacc[i] += __shfl_xor(colacc[i], 32, 64);
    }
    if (q == 0) {
      float* sh = shadow + ((bi & 15) << 9) + c0 + m;
#pragma unroll
      for (int i = 0; i < 8; i++) atomicAdd(&sh[i << 4], colacc[i]);
    }
    if (w == 0) {  // kld_discrete partial: one atomic per block
      float kd = s_kd[lane & 31];
#pragma unroll
      for (int mm = 1; mm < 64; mm <<= 1) kd += __shfl_xor(kd, mm, 64);
      if (lane == 0) atomicAdd(&scal[0], 0.5f * kd);
    }
  }
  __syncthreads();  // B4

  // ---------- in-place transform: e -> er = (e/L)^2 ; se, ce per row ----------
  {
    const float mxr = s_M[row];
    float se = 0.f, ce = 0.f;
    union { v4s v; uint16_t h[4]; } ev, rv;
#pragma unroll
    for (int i = 0; i < 16; i++) {
      const float4 u = gq[i & 3];
      const float uu[4] = {u.x, u.y, u.z, u.w};
      ev.v = *(const v4s*)(l2s + row * L2_STR + (i << 5) + c4);
      if (i < 12) gq[i & 3] = *(const float4*)(gbase + ((i + 4) << 5));
#pragma unroll
      for (int j = 0; j < 4; j++) {
        const float e = bf2f(ev.h[j]);
        const float L = -__logf(uu[j] + 1e-10f) + 1e-10f;
        const float f = __fdividef(e, L);
        const float er = f * f;                 // exp((l2+g)/T), T=0.5
        se += er;
        ce += er * (__logf(e) + mxr);           // er * raw_logit (analytic z.zq)
        rv.h[j] = f2bf(er);
      }
      *(v4s*)(l2s + row * L2_STR + (i << 5) + c4) = rv.v;
    }
    // per-row reductions over the 8 consecutive lanes owning this row
#pragma unroll
    for (int mm = 1; mm < 8; mm <<= 1) { se += __shfl_xor(se, mm, 64); ce += __shfl_xor(ce, mm, 64); }
    float cr = ((t & 7) == 0) ? (ce / se) : 0.f;
#pragma unroll
    for (int mm = 8; mm < 64; mm <<= 1) cr += __shfl_xor(cr, mm, 64);
    if (lane == 0) s_red[w] = cr;
    if ((t & 7) == 0) s_rSe[row] = 1.0f / se;
  }
  __syncthreads();  // B5 — last barrier; MFMA stream below is barrier-free
  if (t == 0) atomicAdd(&scal[2], s_red[0] + s_red[1] + s_red[2] + s_red[3]);

  // ---------- GEMM2: zq = (er @ cbn) / Se — 128 MFMA, no barriers ----------
  v4f acc2a[4], acc2b[4];
#pragma unroll
  for (int i = 0; i < 4; i++) { acc2a[i] = (v4f)0.f; acc2b[i] = (v4f)0.f; }
  {
    const uint16_t* a0p = l2s + m * L2_STR;
    const uint16_t* a1p = l2s + (m + 16) * L2_STR;
#pragma unroll
    for (int cc = 0; cc < 16; cc++) {
      const v8s a0 = *(const v8s*)(a0p + (cc << 5) + (q << 3));
      const v8s a1 = *(const v8s*)(a1p + (cc << 5) + (q << 3));
      const uint16_t* bp2 = cbt2 + (cc << 13) + (w << 9) + (lane << 3);
#pragma unroll
      for (int nt = 0; nt < 4; nt++) {
        const v8s bf = *(const v8s*)(bp2 + (nt << 11));
        acc2a[nt] = __builtin_amdgcn_mfma_f32_16x16x32_bf16(a0, bf, acc2a[nt], 0, 0, 0);
        acc2b[nt] = __builtin_amdgcn_mfma_f32_16x16x32_bf16(a1, bf, acc2b[nt], 0, 0, 0);
      }
    }
  }

  // ---------- epilogue: direct strided stores (write-amp is free at 14% HBM) ----------
  {
    float* ob = out + ((size_t)b << 18) + wh0;
    const int d0 = w << 6;
    float rsA[4], rsB[4];
#pragma unroll
    for (int reg = 0; reg < 4; reg++) {
      rsA[reg] = s_rSe[q * 4 + reg];
      rsB[reg] = s_rSe[16 + q * 4 + reg];
    }
#pragma unroll
    for (int nt = 0; nt < 4; nt++) {
      const int d = d0 + (nt << 4) + m;
#pragma unroll
      for (int reg = 0; reg < 4; reg++) {
        ob[(d << 10) + q * 4 + reg]      = acc2a[nt][reg] * rsA[reg];
        ob[(d << 10) + 16 + q * 4 + reg] = acc2b[nt][reg] * rsB[reg];
      }
    }
  }
}

__global__ __launch_bounds__(512) void vq_final(const float* __restrict__ kappa,
                                                char* __restrict__ ws,
                                                float* __restrict__ out) {
  __shared__ float red[8];
  const int t = threadIdx.x;
  const float* shadow = (const float*)(ws + 524288);
  const float* scal   = (const float*)(ws + 557056);
  float s = 0.f;
#pragma unroll
  for (int j = 0; j < 16; j++) s += shadow[(j << 9) + t];
  float avg = fmaxf(s * (1.0f / 32768.0f), 1e-10f);
  float term = avg * __logf(avg + 1e-10f);
#pragma unroll
  for (int mm = 1; mm < 64; mm <<= 1) term += __shfl_xor(term, mm, 64);
  if ((t & 63) == 0) red[t >> 6] = term;
  __syncthreads();
  if (t == 0) {
    float H = 0.f;
#pragma unroll
    for (int i = 0; i < 8; i++) H += red[i];
    const float perpl = __expf(-H);
    const float kq = fminf(fmaxf(kappa[0], 1e-5f), 1e5f);
    const float loss = (scal[0] + kq * scal[1] - scal[2]) * (1.0f / 32.0f);
    out[8388608] = loss;
    out[8388609] = perpl;
  }
}

extern "C" void kernel_launch(void* const* d_in, const int* in_sizes, int n_in,
                              void* d_out, int out_size, void* d_ws, size_t ws_size,
                              hipStream_t stream) {
  const float* z     = (const float*)d_in[0];
  const float* kappa = (const float*)d_in[1];
  const float* cb    = (const float*)d_in[2];
  const float* gum   = (const float*)d_in[3];
  char* ws = (char*)d_ws;
  float* out = (float*)d_out;
  hipLaunchKernelGGL(vq_prep0, dim3(529),  dim3(64),  0, stream, cb, ws);
  hipLaunchKernelGGL(vq_prep1, dim3(128),  dim3(256), 0, stream, cb, ws);
  hipLaunchKernelGGL(vq_main,  dim3(1024), dim3(256), 0, stream, z, kappa, gum, ws, out);
  hipLaunchKernelGGL(vq_final, dim3(1),    dim3(512), 0, stream, kappa, ws, out);
}